// Round 1
// 3837.439 us; speedup vs baseline: 1.0636x; 1.0636x over previous
//
#include <hip/hip_runtime.h>
#include <stdint.h>
#include <stddef.h>

// Problem dims (fixed)
#define S_LEN 512
#define BATCH 64
#define ISZ   512
#define HID   512
#define NDIR  2

typedef short bf16x8 __attribute__((ext_vector_type(8)));
typedef unsigned short u16x8 __attribute__((ext_vector_type(8)));
typedef float f32x4 __attribute__((ext_vector_type(4)));

// ---- workspace layout (shorts unless noted) ----
// Xb  : [S][4 batch-groups][16*512] bf16, XOR-swizzled 16B units
// hh  : [D][513 slots][4 batch-groups][16*512] bf16, same swizzle (slot 0 = initial_h)
// cnt : int region (memset to 0 each call):
//   [0]          arrival counter (own 128B line)
//   [32+g*32]    per-group monotone publish counter, g = d*4+i (one 128B line each,
//                so fast(L2) and slow(LLC) groups never share a cache line)
//   [288..543]   xcdtab[256] (agent-scope only, startup)
#define XB_ELEMS  ((size_t)S_LEN * 4 * 8192)          // 16,777,216 shorts
#define HH_ELEMS  ((size_t)NDIR * 513 * 4 * 8192)     // 33,619,968 shorts
#define CNT_BYTES ((size_t)16416)                     // keep prior size; first 2176 B used
#define XB_BYTES  (XB_ELEMS * 2)
#define HH_BYTES  (HH_ELEMS * 2)

__device__ __forceinline__ unsigned short f2bf(float f) {
    // round-to-nearest-even fp32 -> bf16 (inputs finite)
    unsigned int u = __float_as_uint(f);
    u += 0x7fffu + ((u >> 16) & 1u);
    return (unsigned short)(u >> 16);
}

// L1-bypass (sc0-only) dword load: reads the XCD-local L2 coherence point.
// waitcnt is inside the asm so the result dependency is self-contained.
__device__ __forceinline__ int l2_load_i32(const int* p) {
    int v;
    asm volatile("global_load_dword %0, %1, off sc0\n\t"
                 "s_waitcnt vmcnt(0)"
                 : "=v"(v) : "v"(p) : "memory");
    return v;
}

// K1: convert X (S,B,I) fp32 -> swizzled bf16 blocks [t][i][b&15][k-units ^ (b&7)]
__global__ void k_convX(const float* __restrict__ X, unsigned short* __restrict__ Xb) {
    int gu = blockIdx.x * 256 + threadIdx.x;       // 2,097,152 units of 8 elems
    int t   = gu >> 12;                            // 4096 units per timestep
    int rem = gu & 4095;
    int b   = rem >> 6;
    int u   = rem & 63;
    const float* src = X + ((size_t)(t * 64 + b)) * 512 + u * 8;
    float4 a = *(const float4*)(src);
    float4 c = *(const float4*)(src + 4);
    u16x8 o;
    o[0]=f2bf(a.x); o[1]=f2bf(a.y); o[2]=f2bf(a.z); o[3]=f2bf(a.w);
    o[4]=f2bf(c.x); o[5]=f2bf(c.y); o[6]=f2bf(c.z); o[7]=f2bf(c.w);
    int i = b >> 4, br = b & 15;
    size_t off = ((size_t)(t * 4 + i)) * 8192 + (size_t)br * 512 + (size_t)((u ^ (b & 7)) << 3);
    *(u16x8*)(Xb + off) = o;
}

// K2: initial_h (D,B,H) fp32 -> hh slot 0 (swizzled bf16)
__global__ void k_initH(const float* __restrict__ h0, unsigned short* __restrict__ hh) {
    int gu = blockIdx.x * 256 + threadIdx.x;       // 8192 units
    int d   = gu >> 12;
    int rem = gu & 4095;
    int b   = rem >> 6;
    int u   = rem & 63;
    const float* src = h0 + ((size_t)(d * 64 + b)) * 512 + u * 8;
    float4 a = *(const float4*)(src);
    float4 c = *(const float4*)(src + 4);
    u16x8 o;
    o[0]=f2bf(a.x); o[1]=f2bf(a.y); o[2]=f2bf(a.z); o[3]=f2bf(a.w);
    o[4]=f2bf(c.x); o[5]=f2bf(c.y); o[6]=f2bf(c.z); o[7]=f2bf(c.w);
    int i = b >> 4, br = b & 15;
    size_t blk = ((size_t)d * 513 + 0) * 4 + i;
    size_t off = blk * 8192 + (size_t)br * 512 + (size_t)((u ^ (b & 7)) << 3);
    *(u16x8*)(hh + off) = o;
}

// Phase 2: persistent bidirectional LSTM. 256 WGs, 256 threads.
// NEW: runtime XCD discovery + role remap. Each sync group (d,i) = 32 blocks.
// If all 32 land on one XCD (the common case at 1 block/CU: 32 CUs/XCD), the
// group's h-exchange runs entirely through that XCD's L2:
//   producer: plain write-through stores + s_waitcnt vmcnt(0) (complete at L2)
//   flag:     workgroup-scope atomic add (global_atomic, no sc1 -> executes at L2)
//   consumer: sc0-only poll load (bypass stale L1, hit L2); plain first-touch
//             data loads (each hh line read exactly once, only after the flag)
// Groups that are not XCD-uniform use the proven LLC-scope (sc0 sc1) path.
__launch_bounds__(256, 1)
__global__ void k_lstm(const float* __restrict__ W, const float* __restrict__ R,
                       const float* __restrict__ Bb, const int* __restrict__ slen,
                       const float* __restrict__ h0g, const float* __restrict__ c0g,
                       const float* __restrict__ P,
                       const unsigned short* __restrict__ Xb,
                       unsigned short* __restrict__ hh,
                       int* __restrict__ cnt,
                       float* __restrict__ Y) {
    __shared__ __align__(16) float gbuf[4 * 256];
    __shared__ int s_xcd[256];
    __shared__ unsigned char s_inv[256];
    __shared__ int s_role, s_fast;

    const int tid = threadIdx.x;
    const int bx  = blockIdx.x;

    int* const arrive = cnt;
    int* const xcdtab = cnt + 288;

    // ---- startup: publish XCC_ID, barrier on all 256 blocks (co-resident:
    // grid == 256 <= capacity; the recurrence spin already requires this) ----
    if (tid == 0) {
        int x;
        asm volatile("s_getreg_b32 %0, hwreg(HW_REG_XCC_ID)" : "=s"(x));
        x &= 0xf;
        __hip_atomic_store(&xcdtab[bx], x + 1, __ATOMIC_RELAXED, __HIP_MEMORY_SCOPE_AGENT);
        asm volatile("s_waitcnt vmcnt(0)" ::: "memory");
        __hip_atomic_fetch_add(arrive, 1, __ATOMIC_RELAXED, __HIP_MEMORY_SCOPE_AGENT);
        int iters = 0;
        while (__hip_atomic_load(arrive, __ATOMIC_RELAXED, __HIP_MEMORY_SCOPE_AGENT) < 256) {
            __builtin_amdgcn_s_sleep(1);
            if (++iters > 2000000) break;   // safety: avoid infinite hang
        }
    }
    __syncthreads();
    s_xcd[tid] = __hip_atomic_load(&xcdtab[tid], __ATOMIC_RELAXED, __HIP_MEMORY_SCOPE_AGENT) - 1;
    __syncthreads();
    {
        // rank of block 'tid' in (xcd, bx) sort order; thread tid computes block tid's rank
        const int myx = s_xcd[tid];
        int r = 0;
        for (int b = 0; b < 256; ++b) {
            const int xb = s_xcd[b];
            r += (int)((xb < myx) | ((xb == myx) & (b < tid)));
        }
        s_inv[r] = (unsigned char)(myx & 0xff);   // ranks are a permutation -> no race
        if (tid == bx) s_role = r;
    }
    __syncthreads();
    if (tid == 0) {
        const int g0 = s_role & ~31;
        int uni = 1;
        for (int q = 1; q < 32; ++q) uni &= (int)(s_inv[g0 + q] == s_inv[g0]);
        int distinct = 1;                         // guard vs a constant (lying) hwreg
        for (int q = 1; q < 256; ++q) distinct += (int)(s_inv[q] != s_inv[q - 1]);
        s_fast = uni & (int)(distinct >= 2);
    }
    __syncthreads();
    const int  role = s_role;
    const bool fast = (s_fast != 0);
    const int  d = role >> 7;
    const int  i = (role >> 5) & 3;
    const int  j = role & 31;
    int* const gcnt = cnt + 32 + ((role >> 5) << 5);   // one 128B line per group

    const int w  = tid >> 6;      // wave = gate  (gate order: [i, o, f, c~])
    const int l  = tid & 63;
    const int lr = l & 15;        // frag row (m for A / n for B)
    const int lq = l >> 4;        // quad -> k offset lq*8

    // ---- permanent weight fragments (bf16) in registers ----
    bf16x8 Wf[16], Rf[16];
    {
        const int row = w * 512 + j * 16 + lr;  // gate-row 0..2047
        const float* wp = W + ((size_t)(d * 2048 + row)) * 512;
        const float* rp = R + ((size_t)(d * 2048 + row)) * 512;
#pragma unroll
        for (int kc = 0; kc < 16; ++kc) {
            int k0 = kc * 32 + lq * 8;
            float4 a = *(const float4*)(wp + k0);
            float4 b4 = *(const float4*)(wp + k0 + 4);
            bf16x8 f;
            f[0]=(short)f2bf(a.x);  f[1]=(short)f2bf(a.y);  f[2]=(short)f2bf(a.z);  f[3]=(short)f2bf(a.w);
            f[4]=(short)f2bf(b4.x); f[5]=(short)f2bf(b4.y); f[6]=(short)f2bf(b4.z); f[7]=(short)f2bf(b4.w);
            Wf[kc] = f;
            a  = *(const float4*)(rp + k0);
            b4 = *(const float4*)(rp + k0 + 4);
            bf16x8 g;
            g[0]=(short)f2bf(a.x);  g[1]=(short)f2bf(a.y);  g[2]=(short)f2bf(a.z);  g[3]=(short)f2bf(a.w);
            g[4]=(short)f2bf(b4.x); g[5]=(short)f2bf(b4.y); g[6]=(short)f2bf(b4.z); g[7]=(short)f2bf(b4.w);
            Rf[kc] = g;
        }
    }

    // ---- per-thread elementwise constants: thread = (batch row eb, h-col ec) ----
    const int eb = tid >> 4;          // 0..15
    const int ec = tid & 15;          // 0..15
    const int bg = i * 16 + eb;       // global batch
    const int kh = j * 16 + ec;       // global h-col
    const float bias_i = Bb[d * 4096 + 0 * 512 + kh] + Bb[d * 4096 + 2048 + 0 * 512 + kh];
    const float bias_o = Bb[d * 4096 + 1 * 512 + kh] + Bb[d * 4096 + 2048 + 1 * 512 + kh];
    const float bias_f = Bb[d * 4096 + 2 * 512 + kh] + Bb[d * 4096 + 2048 + 2 * 512 + kh];
    const float bias_c = Bb[d * 4096 + 3 * 512 + kh] + Bb[d * 4096 + 2048 + 3 * 512 + kh];
    const float Pi = P[d * 1536 + kh];
    const float Pf = P[d * 1536 + 512 + kh];
    const float Po = P[d * 1536 + 1024 + kh];
    const int   sl  = slen[bg];
    const float h0v = h0g[((size_t)d * 64 + bg) * 512 + kh];
    const float c0v = c0g[((size_t)d * 64 + bg) * 512 + kh];
    float c_state = c0v;

    const int rbase = lr * 512;       // row base (shorts) in a tile block
    const int swz   = lr & 7;

    // pack-store constants (even tids): one uint = 2 adjacent h-cols.
    // even tid e packs (own, lane^1) -> same address set as the old 128-packer.
    const int peb = tid >> 4;             // batch row 0..15
    const int cp  = (tid & 15) >> 1;      // pair index 0..7
    const size_t puo = (size_t)peb * 256
                     + (size_t)((((2 * j + (cp >> 2)) ^ (peb & 7)) << 2) + (cp & 3));

    for (int ts = 0; ts < 512; ++ts) {
        const int t = (d == 0) ? ts : (511 - ts);

        // x-GEMM straight from global (cached loads; layout == fragment layout).
        // Runs before the poll -> overlaps waiting on producers (and prefetches
        // the Xb stream into this XCD's L2).
        f32x4 acc = {0.f, 0.f, 0.f, 0.f};
        {
            const unsigned short* xsrc = Xb + ((size_t)(t * 4 + i)) * 8192;
#pragma unroll
            for (int kc = 0; kc < 16; ++kc) {
                int u = (kc * 4 + lq) ^ swz;
                bf16x8 a = *(const bf16x8*)(xsrc + rbase + u * 8);
                acc = __builtin_amdgcn_mfma_f32_16x16x32_bf16(a, Wf[kc], acc, 0, 0, 0);
            }
        }

        // wait for h slot ts (slot 0 pre-filled by k_initH). Single monotone
        // counter per group: slot ts ready <=> counter >= 32*ts.
        if (ts > 0) {
            if (tid == 0) {
                const int target = 32 * ts;
                int iters = 0;
                if (fast) {
                    while (l2_load_i32(gcnt) < target) {          // sc0: L1-bypass, L2-hit
                        __builtin_amdgcn_s_sleep(1);
                        if (++iters > 4000000) break;
                    }
                } else {
                    while (__hip_atomic_load(gcnt, __ATOMIC_RELAXED,
                                             __HIP_MEMORY_SCOPE_AGENT) < target) {
                        __builtin_amdgcn_s_sleep(1);
                        if (++iters > 4000000) break;
                    }
                }
            }
            __syncthreads();
        }

        // h fragments + h-GEMM
        {
            const unsigned short* hsrc16 = hh + (((size_t)d * 513 + ts) * 4 + i) * 8192;
            if (fast) {
                // plain vector loads: every hh line is first-touch on this CU and
                // only reachable after the flag -> L1 can never hold it stale.
                bf16x8 hf[16];
#pragma unroll
                for (int kc = 0; kc < 16; ++kc) {
                    const int u = (kc * 4 + lq) ^ swz;
                    hf[kc] = *(const bf16x8*)(hsrc16 + rbase + u * 8);
                }
#pragma unroll
                for (int kc = 0; kc < 16; ++kc)
                    acc = __builtin_amdgcn_mfma_f32_16x16x32_bf16(hf[kc], Rf[kc], acc, 0, 0, 0);
            } else {
                // proven LLC-scope path (sc0 sc1 dword atomics)
                const unsigned int* hsrc = (const unsigned int*)hsrc16;
                unsigned int hv[64];
#pragma unroll
                for (int kc = 0; kc < 16; ++kc) {
                    int u = (kc * 4 + lq) ^ swz;
                    const unsigned int* p = hsrc + (lr * 256 + u * 4);
                    hv[kc * 4 + 0] = __hip_atomic_load(p + 0, __ATOMIC_RELAXED, __HIP_MEMORY_SCOPE_AGENT);
                    hv[kc * 4 + 1] = __hip_atomic_load(p + 1, __ATOMIC_RELAXED, __HIP_MEMORY_SCOPE_AGENT);
                    hv[kc * 4 + 2] = __hip_atomic_load(p + 2, __ATOMIC_RELAXED, __HIP_MEMORY_SCOPE_AGENT);
                    hv[kc * 4 + 3] = __hip_atomic_load(p + 3, __ATOMIC_RELAXED, __HIP_MEMORY_SCOPE_AGENT);
                }
#pragma unroll
                for (int kc = 0; kc < 16; ++kc) {
                    union { unsigned int u[4]; bf16x8 v; } cvt;
                    cvt.u[0] = hv[kc * 4 + 0];
                    cvt.u[1] = hv[kc * 4 + 1];
                    cvt.u[2] = hv[kc * 4 + 2];
                    cvt.u[3] = hv[kc * 4 + 3];
                    acc = __builtin_amdgcn_mfma_f32_16x16x32_bf16(cvt.v, Rf[kc], acc, 0, 0, 0);
                }
            }
        }

        // exchange gates through LDS: gbuf[gate][b][hc]
#pragma unroll
        for (int r = 0; r < 4; ++r) {
            int b = lq * 4 + r;                    // C/D: row=(lane>>4)*4+reg, col=lane&15
            gbuf[w * 256 + b * 16 + lr] = acc[r];
        }
        __syncthreads();

        // elementwise (one thread per (b, hc))
        float hn, cn;
        {
            float gi = gbuf[0 * 256 + tid] + bias_i;
            float go = gbuf[1 * 256 + tid] + bias_o;
            float gf = gbuf[2 * 256 + tid] + bias_f;
            float gc = gbuf[3 * 256 + tid] + bias_c;
            float c  = c_state;
            float it = 1.f / (1.f + __expf(-(gi + Pi * c)));
            float ft = 1.f / (1.f + __expf(-(gf + Pf * c)));
            float ct = 1.f - 2.f / (__expf(2.f * gc) + 1.f);
            cn = ft * c + it * ct;
            float ot = 1.f / (1.f + __expf(-(go + Po * cn)));
            hn = ot * (1.f - 2.f / (__expf(2.f * cn) + 1.f));
            if (t >= sl) { hn = h0v; cn = c0v; }
            c_state = cn;

            // Y (S,D,B,H) — plain cached stores (visibility via end-of-kernel flush)
            Y[(((size_t)t * 2 + d) * 64 + bg) * 512 + kh] = hn;
            if (ts == 511) {
                Y[(size_t)33554432 + ((size_t)d * 64 + bg) * 512 + kh] = hn;   // Y_h
                Y[(size_t)33619968 + ((size_t)d * 64 + bg) * 512 + kh] = cn;   // Y_c
            }
        }

        // publish h slot ts+1: in-wave shuffle pack (replaces hexch LDS + one
        // barrier). Even lane stores (own | neighbor<<16).
        {
            const unsigned int hb = (unsigned int)f2bf(hn);
            const unsigned int other = (unsigned int)__shfl_xor((int)hb, 1);
            if ((tid & 1) == 0) {
                const unsigned int v = hb | (other << 16);
                unsigned int* hdst =
                    (unsigned int*)(hh + (((size_t)d * 513 + (ts + 1)) * 4 + i) * 8192);
                if (fast) hdst[puo] = v;                     // write-through -> L2
                else __hip_atomic_store(hdst + puo, v, __ATOMIC_RELAXED,
                                        __HIP_MEMORY_SCOPE_AGENT);
            }
        }
        // drain own stores to the coherence point (L2 fast / LLC slow), barrier,
        // then announce.
        asm volatile("s_waitcnt vmcnt(0)" ::: "memory");
        __syncthreads();
        if (tid == 0) {
            if (fast) __hip_atomic_fetch_add(gcnt, 1, __ATOMIC_RELAXED,
                                             __HIP_MEMORY_SCOPE_WORKGROUP);  // L2 RMW
            else      __hip_atomic_fetch_add(gcnt, 1, __ATOMIC_RELAXED,
                                             __HIP_MEMORY_SCOPE_AGENT);      // LLC RMW
        }
    }
}

extern "C" void kernel_launch(void* const* d_in, const int* in_sizes, int n_in,
                              void* d_out, int out_size, void* d_ws, size_t ws_size,
                              hipStream_t stream) {
    const float* X  = (const float*)d_in[0];
    const float* W  = (const float*)d_in[1];
    const float* R  = (const float*)d_in[2];
    const float* Bb = (const float*)d_in[3];
    const int*   sl = (const int*)d_in[4];
    const float* h0 = (const float*)d_in[5];
    const float* c0 = (const float*)d_in[6];
    const float* P  = (const float*)d_in[7];
    float* Y = (float*)d_out;

    unsigned short* Xb  = (unsigned short*)d_ws;
    unsigned short* hh  = (unsigned short*)((char*)d_ws + XB_BYTES);
    int*            cnt = (int*)((char*)d_ws + XB_BYTES + HH_BYTES);

    // zero sync counters + xcd table (ws is poisoned before every timed call)
    hipMemsetAsync(cnt, 0, CNT_BYTES, stream);

    // K1: X -> swizzled bf16
    k_convX<<<8192, 256, 0, stream>>>(X, Xb);
    // K2: initial_h -> hh slot 0
    k_initH<<<32, 256, 0, stream>>>(h0, hh);
    // Phase 2: persistent recurrence (256 WGs)
    k_lstm<<<256, 256, 0, stream>>>(W, R, Bb, sl, h0, c0, P, Xb, hh, cnt, Y);
}

// Round 4
// 3765.484 us; speedup vs baseline: 1.0840x; 1.0191x over previous
//
#include <hip/hip_runtime.h>
#include <stdint.h>
#include <stddef.h>

// Problem dims (fixed)
#define S_LEN 512
#define BATCH 64
#define ISZ   512
#define HID   512
#define NDIR  2

typedef short bf16x8 __attribute__((ext_vector_type(8)));
typedef unsigned short u16x8 __attribute__((ext_vector_type(8)));
typedef float f32x4 __attribute__((ext_vector_type(4)));

// ---- workspace layout (shorts unless noted) ----
// Xb  : [S][4 batch-groups][16*512] bf16, XOR-swizzled 16B units
// hh  : [D][513 slots][4 batch-groups][16*512] bf16, same swizzle (slot 0 = initial_h)
// cnt : int region (memset to 0 each call):
//   [0]            arrival counter (startup barrier)
//   [288..543]     xcdtab[256] (startup)
//   [576 + g*32 + j]  per-(group g, block j) flag dword; one 128B line per group
//                  (cnt+576 is 128B-aligned; 32 dwords = exactly one line)
#define XB_ELEMS  ((size_t)S_LEN * 4 * 8192)          // 16,777,216 shorts
#define HH_ELEMS  ((size_t)NDIR * 513 * 4 * 8192)     // 33,619,968 shorts
#define CNT_BYTES ((size_t)16416)
#define XB_BYTES  (XB_ELEMS * 2)
#define HH_BYTES  (HH_ELEMS * 2)

__device__ __forceinline__ unsigned short f2bf(float f) {
    // round-to-nearest-even fp32 -> bf16 (inputs finite)
    unsigned int u = __float_as_uint(f);
    u += 0x7fffu + ((u >> 16) & 1u);
    return (unsigned short)(u >> 16);
}

// Poll loads. sc0 = bypass L1 (read own-XCD L2 coherence point).
// sc0 sc1 = bypass L1+L2 (read LLC) for the non-uniform fallback.
__device__ __forceinline__ int poll1_l2(const int* p) {
    int v;
    asm volatile("global_load_dword %0, %1, off sc0\n\t"
                 "s_waitcnt vmcnt(0)"
                 : "=&v"(v) : "v"(p) : "memory");
    return v;
}
__device__ __forceinline__ int poll1_llc(const int* p) {
    int v;
    asm volatile("global_load_dword %0, %1, off sc0 sc1\n\t"
                 "s_waitcnt vmcnt(0)"
                 : "=&v"(v) : "v"(p) : "memory");
    return v;
}

// K1: convert X (S,B,I) fp32 -> swizzled bf16 blocks [t][i][b&15][k-units ^ (b&7)]
__global__ void k_convX(const float* __restrict__ X, unsigned short* __restrict__ Xb) {
    int gu = blockIdx.x * 256 + threadIdx.x;       // 2,097,152 units of 8 elems
    int t   = gu >> 12;                            // 4096 units per timestep
    int rem = gu & 4095;
    int b   = rem >> 6;
    int u   = rem & 63;
    const float* src = X + ((size_t)(t * 64 + b)) * 512 + u * 8;
    float4 a = *(const float4*)(src);
    float4 c = *(const float4*)(src + 4);
    u16x8 o;
    o[0]=f2bf(a.x); o[1]=f2bf(a.y); o[2]=f2bf(a.z); o[3]=f2bf(a.w);
    o[4]=f2bf(c.x); o[5]=f2bf(c.y); o[6]=f2bf(c.z); o[7]=f2bf(c.w);
    int i = b >> 4, br = b & 15;
    size_t off = ((size_t)(t * 4 + i)) * 8192 + (size_t)br * 512 + (size_t)((u ^ (b & 7)) << 3);
    *(u16x8*)(Xb + off) = o;
}

// K2: initial_h (D,B,H) fp32 -> hh slot 0 (swizzled bf16)
__global__ void k_initH(const float* __restrict__ h0, unsigned short* __restrict__ hh) {
    int gu = blockIdx.x * 256 + threadIdx.x;       // 8192 units
    int d   = gu >> 12;
    int rem = gu & 4095;
    int b   = rem >> 6;
    int u   = rem & 63;
    const float* src = h0 + ((size_t)(d * 64 + b)) * 512 + u * 8;
    float4 a = *(const float4*)(src);
    float4 c = *(const float4*)(src + 4);
    u16x8 o;
    o[0]=f2bf(a.x); o[1]=f2bf(a.y); o[2]=f2bf(a.z); o[3]=f2bf(a.w);
    o[4]=f2bf(c.x); o[5]=f2bf(c.y); o[6]=f2bf(c.z); o[7]=f2bf(c.w);
    int i = b >> 4, br = b & 15;
    size_t blk = ((size_t)d * 513 + 0) * 4 + i;
    size_t off = blk * 8192 + (size_t)br * 512 + (size_t)((u ^ (b & 7)) << 3);
    *(u16x8*)(hh + off) = o;
}

// Phase 2: persistent bidirectional LSTM. 256 WGs (= 1/CU), 256 threads.
// EXACT round-1 structure (passed @3837us) with ONE isolated change:
// the per-group shared counter (32 same-address atomic fetch_adds per step =
// serialized RMW convoy) is replaced by 32 per-block flag dwords packed in ONE
// 128B line per group.
//   producer: tid 0 plain-stores flag[j]=ts+1 at the exact program point where
//             round 1 did the fetch_add (after vmcnt-drain + __syncthreads).
//   consumer: wave 0 polls; lane l reads flag[l&31] -> the wave's poll is ONE
//             coalesced L2 transaction per iteration (same traffic as round 1's
//             single-dword poll), WITH s_sleep(1) backoff (rounds 2/3 dropped
//             the backoff and starved the producers -> valve timeouts).
// Everything else (hexch publish + its barrier, single accumulator chain,
// Y-store position, slow-path scopes) is byte-identical to round 1.
__launch_bounds__(256, 1)
__global__ void k_lstm(const float* __restrict__ W, const float* __restrict__ R,
                       const float* __restrict__ Bb, const int* __restrict__ slen,
                       const float* __restrict__ h0g, const float* __restrict__ c0g,
                       const float* __restrict__ P,
                       const unsigned short* __restrict__ Xb,
                       unsigned short* __restrict__ hh,
                       int* __restrict__ cnt,
                       float* __restrict__ Y) {
    __shared__ __align__(16) float gbuf[4 * 256];
    __shared__ __align__(4) unsigned short hexch[256];
    __shared__ int s_xcd[256];
    __shared__ unsigned char s_inv[256];
    __shared__ int s_role, s_fast;

    const int tid = threadIdx.x;
    const int bx  = blockIdx.x;

    int* const arrive = cnt;
    int* const xcdtab = cnt + 288;

    // ---- startup: publish XCC_ID, barrier on all 256 blocks (co-resident:
    // grid == 256 <= capacity; the recurrence spin already requires this) ----
    if (tid == 0) {
        int x;
        asm volatile("s_getreg_b32 %0, hwreg(HW_REG_XCC_ID)" : "=s"(x));
        x &= 0xf;
        __hip_atomic_store(&xcdtab[bx], x + 1, __ATOMIC_RELAXED, __HIP_MEMORY_SCOPE_AGENT);
        asm volatile("s_waitcnt vmcnt(0)" ::: "memory");
        __hip_atomic_fetch_add(arrive, 1, __ATOMIC_RELAXED, __HIP_MEMORY_SCOPE_AGENT);
        int iters = 0;
        while (__hip_atomic_load(arrive, __ATOMIC_RELAXED, __HIP_MEMORY_SCOPE_AGENT) < 256) {
            __builtin_amdgcn_s_sleep(1);
            if (++iters > 2000000) break;   // safety: avoid infinite hang
        }
    }
    __syncthreads();
    s_xcd[tid] = __hip_atomic_load(&xcdtab[tid], __ATOMIC_RELAXED, __HIP_MEMORY_SCOPE_AGENT) - 1;
    __syncthreads();
    {
        // rank of block 'tid' in (xcd, bx) sort order; thread tid computes block tid's rank
        const int myx = s_xcd[tid];
        int r = 0;
        for (int b = 0; b < 256; ++b) {
            const int xb = s_xcd[b];
            r += (int)((xb < myx) | ((xb == myx) & (b < tid)));
        }
        s_inv[r] = (unsigned char)(myx & 0xff);   // ranks are a permutation -> no race
        if (tid == bx) s_role = r;
    }
    __syncthreads();
    if (tid == 0) {
        const int g0 = s_role & ~31;
        int uni = 1;
        for (int q = 1; q < 32; ++q) uni &= (int)(s_inv[g0 + q] == s_inv[g0]);
        int distinct = 1;                         // guard vs a constant (lying) hwreg
        for (int q = 1; q < 256; ++q) distinct += (int)(s_inv[q] != s_inv[q - 1]);
        s_fast = uni & (int)(distinct >= 2);
    }
    __syncthreads();
    const int  role = s_role;
    const bool fast = (s_fast != 0);
    const int  d = role >> 7;
    const int  i = (role >> 5) & 3;
    const int  j = role & 31;
    int* const gflags = cnt + 576 + ((role >> 5) << 5);   // 32 flags, one 128B line

    const int w  = tid >> 6;      // wave = gate  (gate order: [i, o, f, c~])
    const int l  = tid & 63;
    const int lr = l & 15;        // frag row (m for A / n for B)
    const int lq = l >> 4;        // quad -> k offset lq*8

    // ---- permanent weight fragments (bf16) in registers ----
    bf16x8 Wf[16], Rf[16];
    {
        const int row = w * 512 + j * 16 + lr;  // gate-row 0..2047
        const float* wp = W + ((size_t)(d * 2048 + row)) * 512;
        const float* rp = R + ((size_t)(d * 2048 + row)) * 512;
#pragma unroll
        for (int kc = 0; kc < 16; ++kc) {
            int k0 = kc * 32 + lq * 8;
            float4 a = *(const float4*)(wp + k0);
            float4 b4 = *(const float4*)(wp + k0 + 4);
            bf16x8 f;
            f[0]=(short)f2bf(a.x);  f[1]=(short)f2bf(a.y);  f[2]=(short)f2bf(a.z);  f[3]=(short)f2bf(a.w);
            f[4]=(short)f2bf(b4.x); f[5]=(short)f2bf(b4.y); f[6]=(short)f2bf(b4.z); f[7]=(short)f2bf(b4.w);
            Wf[kc] = f;
            a  = *(const float4*)(rp + k0);
            b4 = *(const float4*)(rp + k0 + 4);
            bf16x8 g;
            g[0]=(short)f2bf(a.x);  g[1]=(short)f2bf(a.y);  g[2]=(short)f2bf(a.z);  g[3]=(short)f2bf(a.w);
            g[4]=(short)f2bf(b4.x); g[5]=(short)f2bf(b4.y); g[6]=(short)f2bf(b4.z); g[7]=(short)f2bf(b4.w);
            Rf[kc] = g;
        }
    }

    // ---- per-thread elementwise constants: thread = (batch row eb, h-col ec) ----
    const int eb = tid >> 4;          // 0..15
    const int ec = tid & 15;          // 0..15
    const int bg = i * 16 + eb;       // global batch
    const int kh = j * 16 + ec;       // global h-col
    const float bias_i = Bb[d * 4096 + 0 * 512 + kh] + Bb[d * 4096 + 2048 + 0 * 512 + kh];
    const float bias_o = Bb[d * 4096 + 1 * 512 + kh] + Bb[d * 4096 + 2048 + 1 * 512 + kh];
    const float bias_f = Bb[d * 4096 + 2 * 512 + kh] + Bb[d * 4096 + 2048 + 2 * 512 + kh];
    const float bias_c = Bb[d * 4096 + 3 * 512 + kh] + Bb[d * 4096 + 2048 + 3 * 512 + kh];
    const float Pi = P[d * 1536 + kh];
    const float Pf = P[d * 1536 + 512 + kh];
    const float Po = P[d * 1536 + 1024 + kh];
    const int   sl  = slen[bg];
    const float h0v = h0g[((size_t)d * 64 + bg) * 512 + kh];
    const float c0v = c0g[((size_t)d * 64 + bg) * 512 + kh];
    float c_state = c0v;

    const int rbase = lr * 512;       // row base (shorts) in a tile block
    const int swz   = lr & 7;

    // pack-store constants (threads 0..127): one uint = 2 adjacent h-cols
    const int peb = tid >> 3;         // batch row 0..15
    const int pm  = tid & 7;          // uint-pair index within row
    const size_t puo = (size_t)peb * 256
                     + (size_t)((((2 * j + (pm >> 2)) ^ (peb & 7)) << 2) + (pm & 3));

    // own flag (tid 0 stores); poll addr for wave-0 lanes (lane l -> block l&31)
    int* const myflag = gflags + j;
    const int* const pollp = gflags + (l & 31);

    for (int ts = 0; ts < 512; ++ts) {
        const int t = (d == 0) ? ts : (511 - ts);

        // x-GEMM straight from global (cached loads; layout == fragment layout).
        // Runs before the poll -> overlaps waiting on producers.
        f32x4 acc = {0.f, 0.f, 0.f, 0.f};
        {
            const unsigned short* xsrc = Xb + ((size_t)(t * 4 + i)) * 8192;
#pragma unroll
            for (int kc = 0; kc < 16; ++kc) {
                int u = (kc * 4 + lq) ^ swz;
                bf16x8 a = *(const bf16x8*)(xsrc + rbase + u * 8);
                acc = __builtin_amdgcn_mfma_f32_16x16x32_bf16(a, Wf[kc], acc, 0, 0, 0);
            }
        }

        // wait for h slot ts: all 32 per-block flags of this group >= ts.
        // Wave 0 polls: lane l covers flag l&31 -> ONE coalesced L2 transaction
        // per iteration, s_sleep(1) backoff (round-1 discipline). Then barrier.
        if (ts > 0) {
            if (w == 0) {
                int iters = 0;
                if (fast) {
                    for (;;) {
                        int v = poll1_l2(pollp);
                        if (__all(v >= ts)) break;
                        __builtin_amdgcn_s_sleep(1);
                        if (++iters > 4000000) break;   // safety: avoid infinite hang
                    }
                } else {
                    for (;;) {
                        int v = poll1_llc(pollp);
                        if (__all(v >= ts)) break;
                        __builtin_amdgcn_s_sleep(1);
                        if (++iters > 4000000) break;
                    }
                }
            }
            __syncthreads();
        }

        // h fragments + h-GEMM
        {
            const unsigned short* hsrc16 = hh + (((size_t)d * 513 + ts) * 4 + i) * 8192;
            if (fast) {
                // plain vector loads: every hh line is first-touch on this CU and
                // only reachable after the flag -> L1 can never hold it stale.
                bf16x8 hf[16];
#pragma unroll
                for (int kc = 0; kc < 16; ++kc) {
                    const int u = (kc * 4 + lq) ^ swz;
                    hf[kc] = *(const bf16x8*)(hsrc16 + rbase + u * 8);
                }
#pragma unroll
                for (int kc = 0; kc < 16; ++kc)
                    acc = __builtin_amdgcn_mfma_f32_16x16x32_bf16(hf[kc], Rf[kc], acc, 0, 0, 0);
            } else {
                // LLC-scope fallback (sc0 sc1 dword atomic loads)
                const unsigned int* hsrc = (const unsigned int*)hsrc16;
                unsigned int hv[64];
#pragma unroll
                for (int kc = 0; kc < 16; ++kc) {
                    int u = (kc * 4 + lq) ^ swz;
                    const unsigned int* p = hsrc + (lr * 256 + u * 4);
                    hv[kc * 4 + 0] = __hip_atomic_load(p + 0, __ATOMIC_RELAXED, __HIP_MEMORY_SCOPE_AGENT);
                    hv[kc * 4 + 1] = __hip_atomic_load(p + 1, __ATOMIC_RELAXED, __HIP_MEMORY_SCOPE_AGENT);
                    hv[kc * 4 + 2] = __hip_atomic_load(p + 2, __ATOMIC_RELAXED, __HIP_MEMORY_SCOPE_AGENT);
                    hv[kc * 4 + 3] = __hip_atomic_load(p + 3, __ATOMIC_RELAXED, __HIP_MEMORY_SCOPE_AGENT);
                }
#pragma unroll
                for (int kc = 0; kc < 16; ++kc) {
                    union { unsigned int u[4]; bf16x8 v; } cvt;
                    cvt.u[0] = hv[kc * 4 + 0];
                    cvt.u[1] = hv[kc * 4 + 1];
                    cvt.u[2] = hv[kc * 4 + 2];
                    cvt.u[3] = hv[kc * 4 + 3];
                    acc = __builtin_amdgcn_mfma_f32_16x16x32_bf16(cvt.v, Rf[kc], acc, 0, 0, 0);
                }
            }
        }

        // exchange gates through LDS: gbuf[gate][b][hc]
#pragma unroll
        for (int r = 0; r < 4; ++r) {
            int b = lq * 4 + r;                    // C/D: row=(lane>>4)*4+reg, col=lane&15
            gbuf[w * 256 + b * 16 + lr] = acc[r];
        }
        __syncthreads();

        // elementwise (one thread per (b, hc))
        float hn, cn;
        {
            float gi = gbuf[0 * 256 + tid] + bias_i;
            float go = gbuf[1 * 256 + tid] + bias_o;
            float gf = gbuf[2 * 256 + tid] + bias_f;
            float gc = gbuf[3 * 256 + tid] + bias_c;
            float c  = c_state;
            float it = 1.f / (1.f + __expf(-(gi + Pi * c)));
            float ft = 1.f / (1.f + __expf(-(gf + Pf * c)));
            float ct = 1.f - 2.f / (__expf(2.f * gc) + 1.f);
            cn = ft * c + it * ct;
            float ot = 1.f / (1.f + __expf(-(go + Po * cn)));
            hn = ot * (1.f - 2.f / (__expf(2.f * cn) + 1.f));
            if (t >= sl) { hn = h0v; cn = c0v; }
            c_state = cn;

            // Y (S,D,B,H) — plain cached stores (visibility via end-of-kernel flush)
            Y[(((size_t)t * 2 + d) * 64 + bg) * 512 + kh] = hn;
            if (ts == 511) {
                Y[(size_t)33554432 + ((size_t)d * 64 + bg) * 512 + kh] = hn;   // Y_h
                Y[(size_t)33619968 + ((size_t)d * 64 + bg) * 512 + kh] = cn;   // Y_c
            }
            hexch[tid] = f2bf(hn);
        }
        __syncthreads();

        // publish h slot ts+1: threads 0..127 pack 2 bf16 -> uint
        if (tid < 128) {
            unsigned int v = ((const unsigned int*)hexch)[tid];
            unsigned int* hdst =
                (unsigned int*)(hh + (((size_t)d * 513 + (ts + 1)) * 4 + i) * 8192);
            if (fast) hdst[puo] = v;                     // write-through -> L2
            else __hip_atomic_store(hdst + puo, v, __ATOMIC_RELAXED,
                                    __HIP_MEMORY_SCOPE_AGENT);
        }
        // drain own stores to the coherence point, block-wide barrier, then the
        // per-block flag (plain store — NO RMW). Same program point as round 1's
        // fetch_add.
        asm volatile("s_waitcnt vmcnt(0)" ::: "memory");
        __syncthreads();
        if (tid == 0) {
            if (fast) __hip_atomic_store(myflag, ts + 1, __ATOMIC_RELAXED,
                                         __HIP_MEMORY_SCOPE_WORKGROUP);  // plain store -> L2
            else      __hip_atomic_store(myflag, ts + 1, __ATOMIC_RELAXED,
                                         __HIP_MEMORY_SCOPE_AGENT);      // sc0 sc1 -> LLC
        }
    }
}

extern "C" void kernel_launch(void* const* d_in, const int* in_sizes, int n_in,
                              void* d_out, int out_size, void* d_ws, size_t ws_size,
                              hipStream_t stream) {
    const float* X  = (const float*)d_in[0];
    const float* W  = (const float*)d_in[1];
    const float* R  = (const float*)d_in[2];
    const float* Bb = (const float*)d_in[3];
    const int*   sl = (const int*)d_in[4];
    const float* h0 = (const float*)d_in[5];
    const float* c0 = (const float*)d_in[6];
    const float* P  = (const float*)d_in[7];
    float* Y = (float*)d_out;

    unsigned short* Xb  = (unsigned short*)d_ws;
    unsigned short* hh  = (unsigned short*)((char*)d_ws + XB_BYTES);
    int*            cnt = (int*)((char*)d_ws + XB_BYTES + HH_BYTES);

    // zero sync flags + xcd table (ws is poisoned before every timed call)
    hipMemsetAsync(cnt, 0, CNT_BYTES, stream);

    // K1: X -> swizzled bf16
    k_convX<<<8192, 256, 0, stream>>>(X, Xb);
    // K2: initial_h -> hh slot 0
    k_initH<<<32, 256, 0, stream>>>(h0, hh);
    // Phase 2: persistent recurrence (256 WGs)
    k_lstm<<<256, 256, 0, stream>>>(W, R, Bb, sl, h0, c0, P, Xb, hh, cnt, Y);
}

// Round 5
// 3721.811 us; speedup vs baseline: 1.0967x; 1.0117x over previous
//
#include <hip/hip_runtime.h>
#include <stdint.h>
#include <stddef.h>

// Problem dims (fixed)
#define S_LEN 512
#define BATCH 64
#define ISZ   512
#define HID   512
#define NDIR  2

typedef short bf16x8 __attribute__((ext_vector_type(8)));
typedef unsigned short u16x8 __attribute__((ext_vector_type(8)));
typedef float f32x4 __attribute__((ext_vector_type(4)));
typedef int   i32x2 __attribute__((ext_vector_type(2)));

// ---- workspace layout (shorts unless noted) ----
// Xb  : [S][4 batch-groups][16*512] bf16, XOR-swizzled 16B units
// hh  : [D][513 slots][4 batch-groups][16*512] bf16, same swizzle (slot 0 = initial_h)
// cnt : int region (memset to 0 each call):
//   [0]            arrival counter (startup barrier)
//   [288..543]     xcdtab[256] (startup)
//   [576 + g*128 + (j*4+w)]  per-(group g, block j, wave w) flag dword
//                  (128 dwords = 4 cache lines per group)
#define XB_ELEMS  ((size_t)S_LEN * 4 * 8192)          // 16,777,216 shorts
#define HH_ELEMS  ((size_t)NDIR * 513 * 4 * 8192)     // 33,619,968 shorts
#define CNT_BYTES ((size_t)16416)
#define XB_BYTES  (XB_ELEMS * 2)
#define HH_BYTES  (HH_ELEMS * 2)

__device__ __forceinline__ unsigned short f2bf(float f) {
    // round-to-nearest-even fp32 -> bf16 (inputs finite)
    unsigned int u = __float_as_uint(f);
    u += 0x7fffu + ((u >> 16) & 1u);
    return (unsigned short)(u >> 16);
}

// Poll loads. sc0 = bypass L1 (read own-XCD L2 coherence point).
// sc0 sc1 = bypass L1+L2 (read LLC) for the non-uniform fallback.
__device__ __forceinline__ i32x2 poll2_l2(const int* p) {
    i32x2 v;
    asm volatile("global_load_dwordx2 %0, %1, off sc0\n\t"
                 "s_waitcnt vmcnt(0)"
                 : "=&v"(v) : "v"(p) : "memory");
    return v;
}
__device__ __forceinline__ i32x2 poll2_llc(const int* p) {
    i32x2 v;
    asm volatile("global_load_dwordx2 %0, %1, off sc0 sc1\n\t"
                 "s_waitcnt vmcnt(0)"
                 : "=&v"(v) : "v"(p) : "memory");
    return v;
}

// K1: convert X (S,B,I) fp32 -> swizzled bf16 blocks [t][i][b&15][k-units ^ (b&7)]
__global__ void k_convX(const float* __restrict__ X, unsigned short* __restrict__ Xb) {
    int gu = blockIdx.x * 256 + threadIdx.x;       // 2,097,152 units of 8 elems
    int t   = gu >> 12;                            // 4096 units per timestep
    int rem = gu & 4095;
    int b   = rem >> 6;
    int u   = rem & 63;
    const float* src = X + ((size_t)(t * 64 + b)) * 512 + u * 8;
    float4 a = *(const float4*)(src);
    float4 c = *(const float4*)(src + 4);
    u16x8 o;
    o[0]=f2bf(a.x); o[1]=f2bf(a.y); o[2]=f2bf(a.z); o[3]=f2bf(a.w);
    o[4]=f2bf(c.x); o[5]=f2bf(c.y); o[6]=f2bf(c.z); o[7]=f2bf(c.w);
    int i = b >> 4, br = b & 15;
    size_t off = ((size_t)(t * 4 + i)) * 8192 + (size_t)br * 512 + (size_t)((u ^ (b & 7)) << 3);
    *(u16x8*)(Xb + off) = o;
}

// K2: initial_h (D,B,H) fp32 -> hh slot 0 (swizzled bf16)
__global__ void k_initH(const float* __restrict__ h0, unsigned short* __restrict__ hh) {
    int gu = blockIdx.x * 256 + threadIdx.x;       // 8192 units
    int d   = gu >> 12;
    int rem = gu & 4095;
    int b   = rem >> 6;
    int u   = rem & 63;
    const float* src = h0 + ((size_t)(d * 64 + b)) * 512 + u * 8;
    float4 a = *(const float4*)(src);
    float4 c = *(const float4*)(src + 4);
    u16x8 o;
    o[0]=f2bf(a.x); o[1]=f2bf(a.y); o[2]=f2bf(a.z); o[3]=f2bf(a.w);
    o[4]=f2bf(c.x); o[5]=f2bf(c.y); o[6]=f2bf(c.z); o[7]=f2bf(c.w);
    int i = b >> 4, br = b & 15;
    size_t blk = ((size_t)d * 513 + 0) * 4 + i;
    size_t off = blk * 8192 + (size_t)br * 512 + (size_t)((u ^ (b & 7)) << 3);
    *(u16x8*)(hh + off) = o;
}

// Phase 2: persistent bidirectional LSTM. 256 WGs (= 1/CU), 256 threads.
// Round 5: BARRIER-FREE step via wave-autonomous design.
//   - Mixed-gate B-fragments: wave w's 16 MFMA output columns = {gate 0..3} x
//     {h-col w*4..w*4+3} (B-frag row per lane: g*512 + j*16 + w*4 + sub).
//     One wave therefore owns ALL 4 gates of its 4 h-cols -> the gate exchange
//     is WAVE-LOCAL: ds_write_b128 + 4 LDS reads in a private strip, no barrier
//     (same-wave LDS ops are program-ordered).
//   - Each wave: elementwise (1 (b,col)/lane) -> shfl_xor(16) col-pair pack ->
//     publish own 128 B -> vmcnt(0) -> own per-wave flag (plain store, no RMW).
//   - Consumers poll all 128 wave-flags (dwordx2/lane + __all) WITH s_sleep(1)
//     backoff (sleepless polling self-starved in rounds 2/3).
//   - ZERO __syncthreads in the loop. Safe: hh slots are write-once per ts,
//     flags are monotone and gate every hh read; no shared LDS remains.
//   - Y stores issued after the flag (off the serial path).
__launch_bounds__(256, 1)
__global__ void k_lstm(const float* __restrict__ W, const float* __restrict__ R,
                       const float* __restrict__ Bb, const int* __restrict__ slen,
                       const float* __restrict__ h0g, const float* __restrict__ c0g,
                       const float* __restrict__ P,
                       const unsigned short* __restrict__ Xb,
                       unsigned short* __restrict__ hh,
                       int* __restrict__ cnt,
                       float* __restrict__ Y) {
    __shared__ __align__(16) float xbuf[4 * 256];   // per-wave 256-float strips
    __shared__ int s_xcd[256];
    __shared__ unsigned char s_inv[256];
    __shared__ int s_role, s_fast;

    const int tid = threadIdx.x;
    const int bx  = blockIdx.x;

    int* const arrive = cnt;
    int* const xcdtab = cnt + 288;

    // ---- startup: publish XCC_ID, barrier on all 256 blocks (co-resident:
    // grid == 256 <= capacity; the recurrence spin already requires this) ----
    if (tid == 0) {
        int x;
        asm volatile("s_getreg_b32 %0, hwreg(HW_REG_XCC_ID)" : "=s"(x));
        x &= 0xf;
        __hip_atomic_store(&xcdtab[bx], x + 1, __ATOMIC_RELAXED, __HIP_MEMORY_SCOPE_AGENT);
        asm volatile("s_waitcnt vmcnt(0)" ::: "memory");
        __hip_atomic_fetch_add(arrive, 1, __ATOMIC_RELAXED, __HIP_MEMORY_SCOPE_AGENT);
        int iters = 0;
        while (__hip_atomic_load(arrive, __ATOMIC_RELAXED, __HIP_MEMORY_SCOPE_AGENT) < 256) {
            __builtin_amdgcn_s_sleep(1);
            if (++iters > 2000000) break;   // safety: avoid infinite hang
        }
    }
    __syncthreads();
    s_xcd[tid] = __hip_atomic_load(&xcdtab[tid], __ATOMIC_RELAXED, __HIP_MEMORY_SCOPE_AGENT) - 1;
    __syncthreads();
    {
        // rank of block 'tid' in (xcd, bx) sort order; thread tid computes block tid's rank
        const int myx = s_xcd[tid];
        int r = 0;
        for (int b = 0; b < 256; ++b) {
            const int xb = s_xcd[b];
            r += (int)((xb < myx) | ((xb == myx) & (b < tid)));
        }
        s_inv[r] = (unsigned char)(myx & 0xff);   // ranks are a permutation -> no race
        if (tid == bx) s_role = r;
    }
    __syncthreads();
    if (tid == 0) {
        const int g0 = s_role & ~31;
        int uni = 1;
        for (int q = 1; q < 32; ++q) uni &= (int)(s_inv[g0 + q] == s_inv[g0]);
        int distinct = 1;                         // guard vs a constant (lying) hwreg
        for (int q = 1; q < 256; ++q) distinct += (int)(s_inv[q] != s_inv[q - 1]);
        s_fast = uni & (int)(distinct >= 2);
    }
    __syncthreads();
    const int  role = s_role;
    const bool fast = (s_fast != 0);
    const int  d = role >> 7;
    const int  i = (role >> 5) & 3;
    const int  j = role & 31;
    int* const gflags = cnt + 576 + ((role >> 5) << 7);   // 128 wave-flags per group

    const int w  = tid >> 6;      // wave -> 4 h-cols (all 4 gates)
    const int l  = tid & 63;
    const int n  = l & 15;        // MFMA B-lane / A-row field
    const int q  = l >> 4;        // k-slice quad

    // B-lane decomposition: gate gsel, col-within-wave csel
    const int gsel = n & 3;
    const int csel = n >> 2;

    // ---- permanent weight fragments (bf16) in registers: mixed-gate rows ----
    bf16x8 Wf[16], Rf[16];
    {
        const int row = gsel * 512 + j * 16 + w * 4 + csel;  // absolute gate-row
        const float* wp = W + ((size_t)(d * 2048 + row)) * 512;
        const float* rp = R + ((size_t)(d * 2048 + row)) * 512;
#pragma unroll
        for (int kc = 0; kc < 16; ++kc) {
            int k0 = kc * 32 + q * 8;
            float4 a = *(const float4*)(wp + k0);
            float4 b4 = *(const float4*)(wp + k0 + 4);
            bf16x8 f;
            f[0]=(short)f2bf(a.x);  f[1]=(short)f2bf(a.y);  f[2]=(short)f2bf(a.z);  f[3]=(short)f2bf(a.w);
            f[4]=(short)f2bf(b4.x); f[5]=(short)f2bf(b4.y); f[6]=(short)f2bf(b4.z); f[7]=(short)f2bf(b4.w);
            Wf[kc] = f;
            a  = *(const float4*)(rp + k0);
            b4 = *(const float4*)(rp + k0 + 4);
            bf16x8 g;
            g[0]=(short)f2bf(a.x);  g[1]=(short)f2bf(a.y);  g[2]=(short)f2bf(a.z);  g[3]=(short)f2bf(a.w);
            g[4]=(short)f2bf(b4.x); g[5]=(short)f2bf(b4.y); g[6]=(short)f2bf(b4.z); g[7]=(short)f2bf(b4.w);
            Rf[kc] = g;
        }
    }

    // ---- post-exchange per-lane assignment: (batch bloc, col cloc) ----
    const int bloc = l & 15;          // batch row 0..15
    const int cloc = l >> 4;          // col-within-wave 0..3
    const int bg = i * 16 + bloc;     // global batch
    const int kh = j * 16 + w * 4 + cloc;   // global h-col
    const float bias_i = Bb[d * 4096 + 0 * 512 + kh] + Bb[d * 4096 + 2048 + 0 * 512 + kh];
    const float bias_o = Bb[d * 4096 + 1 * 512 + kh] + Bb[d * 4096 + 2048 + 1 * 512 + kh];
    const float bias_f = Bb[d * 4096 + 2 * 512 + kh] + Bb[d * 4096 + 2048 + 2 * 512 + kh];
    const float bias_c = Bb[d * 4096 + 3 * 512 + kh] + Bb[d * 4096 + 2048 + 3 * 512 + kh];
    const float Pi = P[d * 1536 + kh];
    const float Pf = P[d * 1536 + 512 + kh];
    const float Po = P[d * 1536 + 1024 + kh];
    const int   sl  = slen[bg];
    const float h0v = h0g[((size_t)d * 64 + bg) * 512 + kh];
    const float c0v = c0g[((size_t)d * 64 + bg) * 512 + kh];
    float c_state = c0v;

    const int rbase = n * 512;        // A-frag row base (shorts) in a tile block
    const int swz   = n & 7;

    // exchange strip addresses (wave-local)
    const int wrb = w * 256 + csel * 64 + gsel * 16 + q * 4;   // ds_write_b128 base
    const int erb = w * 256 + cloc * 64 + bloc;                // read base (+16*g)

    // publish constants: even-col lanes store one uint = cols (cloc, cloc+1)
    const int pm  = w * 2 + (cloc >> 1);   // col-pair index within block's 16 cols
    const size_t puo = (size_t)bloc * 256
                     + (size_t)((((2 * j + (pm >> 2)) ^ (bloc & 7)) << 2) + (pm & 3));

    // own per-wave flag; poll covers all 128 flags (lane l -> flags 2l, 2l+1)
    int* const myflag = gflags + (j * 4 + w);
    const int* const pollp = gflags + 2 * l;

    for (int ts = 0; ts < 512; ++ts) {
        const int t = (d == 0) ? ts : (511 - ts);

        // 1. x-GEMM straight from global (cached loads; layout == fragment layout).
        //    Runs before the poll -> overlaps waiting on producers.
        f32x4 acc0 = {0.f, 0.f, 0.f, 0.f};
        f32x4 acc1 = {0.f, 0.f, 0.f, 0.f};
        {
            const unsigned short* xsrc = Xb + ((size_t)(t * 4 + i)) * 8192;
#pragma unroll
            for (int kc = 0; kc < 16; ++kc) {
                int u = (kc * 4 + q) ^ swz;
                bf16x8 a = *(const bf16x8*)(xsrc + rbase + u * 8);
                if (kc & 1) acc1 = __builtin_amdgcn_mfma_f32_16x16x32_bf16(a, Wf[kc], acc1, 0, 0, 0);
                else        acc0 = __builtin_amdgcn_mfma_f32_16x16x32_bf16(a, Wf[kc], acc0, 0, 0, 0);
            }
        }

        // 2. wait for h slot ts: all 128 per-wave flags of this group >= ts.
        //    Every wave polls independently; s_sleep(1) backoff (mandatory).
        if (ts > 0) {
            int iters = 0;
            if (fast) {
                for (;;) {
                    i32x2 f = poll2_l2(pollp);
                    if (__all((f.x >= ts) & (f.y >= ts))) break;
                    __builtin_amdgcn_s_sleep(1);
                    if (++iters > 4000000) break;   // safety: avoid infinite hang
                }
            } else {
                for (;;) {
                    i32x2 f = poll2_llc(pollp);
                    if (__all((f.x >= ts) & (f.y >= ts))) break;
                    __builtin_amdgcn_s_sleep(1);
                    if (++iters > 4000000) break;
                }
            }
        }

        // 3. h fragments + h-GEMM
        {
            const unsigned short* hsrc16 = hh + (((size_t)d * 513 + ts) * 4 + i) * 8192;
            if (fast) {
                // plain vector loads: every hh line is first-touch on this CU and
                // only reachable after the flag -> L1 can never hold it stale.
                bf16x8 hf[16];
#pragma unroll
                for (int kc = 0; kc < 16; ++kc) {
                    const int u = (kc * 4 + q) ^ swz;
                    hf[kc] = *(const bf16x8*)(hsrc16 + rbase + u * 8);
                }
#pragma unroll
                for (int kc = 0; kc < 16; ++kc) {
                    if (kc & 1) acc1 = __builtin_amdgcn_mfma_f32_16x16x32_bf16(hf[kc], Rf[kc], acc1, 0, 0, 0);
                    else        acc0 = __builtin_amdgcn_mfma_f32_16x16x32_bf16(hf[kc], Rf[kc], acc0, 0, 0, 0);
                }
            } else {
                // LLC-scope fallback (sc0 sc1 dword atomic loads)
                const unsigned int* hsrc = (const unsigned int*)hsrc16;
                unsigned int hv[64];
#pragma unroll
                for (int kc = 0; kc < 16; ++kc) {
                    int u = (kc * 4 + q) ^ swz;
                    const unsigned int* p = hsrc + (n * 256 + u * 4);
                    hv[kc * 4 + 0] = __hip_atomic_load(p + 0, __ATOMIC_RELAXED, __HIP_MEMORY_SCOPE_AGENT);
                    hv[kc * 4 + 1] = __hip_atomic_load(p + 1, __ATOMIC_RELAXED, __HIP_MEMORY_SCOPE_AGENT);
                    hv[kc * 4 + 2] = __hip_atomic_load(p + 2, __ATOMIC_RELAXED, __HIP_MEMORY_SCOPE_AGENT);
                    hv[kc * 4 + 3] = __hip_atomic_load(p + 3, __ATOMIC_RELAXED, __HIP_MEMORY_SCOPE_AGENT);
                }
#pragma unroll
                for (int kc = 0; kc < 16; ++kc) {
                    union { unsigned int u[4]; bf16x8 v; } cvt;
                    cvt.u[0] = hv[kc * 4 + 0];
                    cvt.u[1] = hv[kc * 4 + 1];
                    cvt.u[2] = hv[kc * 4 + 2];
                    cvt.u[3] = hv[kc * 4 + 3];
                    if (kc & 1) acc1 = __builtin_amdgcn_mfma_f32_16x16x32_bf16(cvt.v, Rf[kc], acc1, 0, 0, 0);
                    else        acc0 = __builtin_amdgcn_mfma_f32_16x16x32_bf16(cvt.v, Rf[kc], acc0, 0, 0, 0);
                }
            }
        }

        // 4. WAVE-LOCAL gate exchange (no barrier): one ds_write_b128, 4 reads.
        {
            f32x4 accs = acc0 + acc1;
            *(f32x4*)&xbuf[wrb] = accs;     // [col][gate][batch] within wave strip
        }
        const float g0 = xbuf[erb];          // gate i
        const float g1 = xbuf[erb + 16];     // gate o
        const float g2 = xbuf[erb + 32];     // gate f
        const float g3 = xbuf[erb + 48];     // gate c~

        // 5. elementwise: one (batch, col) pair per lane
        float hn, cn;
        {
            float gi = g0 + bias_i;
            float go = g1 + bias_o;
            float gf = g2 + bias_f;
            float gc = g3 + bias_c;
            float c  = c_state;
            float it = 1.f / (1.f + __expf(-(gi + Pi * c)));
            float ft = 1.f / (1.f + __expf(-(gf + Pf * c)));
            float ct = 1.f - 2.f / (__expf(2.f * gc) + 1.f);
            cn = ft * c + it * ct;
            float ot = 1.f / (1.f + __expf(-(go + Po * cn)));
            hn = ot * (1.f - 2.f / (__expf(2.f * cn) + 1.f));
            if (t >= sl) { hn = h0v; cn = c0v; }
            c_state = cn;
        }

        // 6. publish h slot ts+1: pair cols via shfl_xor(16); even-col lanes
        //    store one uint (low short = even col).
        const float hoth = __shfl_xor(hn, 16);
        if ((l & 16) == 0) {
            const unsigned int v = (unsigned int)f2bf(hn)
                                 | ((unsigned int)f2bf(hoth) << 16);
            unsigned int* hdst =
                (unsigned int*)(hh + (((size_t)d * 513 + (ts + 1)) * 4 + i) * 8192);
            if (fast) hdst[puo] = v;                     // write-through -> L2
            else __hip_atomic_store(hdst + puo, v, __ATOMIC_RELAXED,
                                    __HIP_MEMORY_SCOPE_AGENT);
        }
        // 7. drain own publish store, then raise this wave's flag (plain store).
        asm volatile("s_waitcnt vmcnt(0)" ::: "memory");
        if (l == 0) {
            if (fast) __hip_atomic_store(myflag, ts + 1, __ATOMIC_RELAXED,
                                         __HIP_MEMORY_SCOPE_WORKGROUP);  // -> L2
            else      __hip_atomic_store(myflag, ts + 1, __ATOMIC_RELAXED,
                                         __HIP_MEMORY_SCOPE_AGENT);      // -> LLC
        }

        // 8. Y stores (off the critical path; visibility via end-of-kernel flush)
        if ((l & 16) == 0) {
            float2 yv; yv.x = hn; yv.y = hoth;
            *(float2*)(Y + (((size_t)t * 2 + d) * 64 + bg) * 512 + kh) = yv;
        }
        if (ts == 511) {
            const float coth = __shfl_xor(cn, 16);
            if ((l & 16) == 0) {
                float2 yh; yh.x = hn; yh.y = hoth;
                float2 yc; yc.x = cn; yc.y = coth;
                *(float2*)(Y + (size_t)33554432 + ((size_t)d * 64 + bg) * 512 + kh) = yh;
                *(float2*)(Y + (size_t)33619968 + ((size_t)d * 64 + bg) * 512 + kh) = yc;
            }
        }
    }
}

extern "C" void kernel_launch(void* const* d_in, const int* in_sizes, int n_in,
                              void* d_out, int out_size, void* d_ws, size_t ws_size,
                              hipStream_t stream) {
    const float* X  = (const float*)d_in[0];
    const float* W  = (const float*)d_in[1];
    const float* R  = (const float*)d_in[2];
    const float* Bb = (const float*)d_in[3];
    const int*   sl = (const int*)d_in[4];
    const float* h0 = (const float*)d_in[5];
    const float* c0 = (const float*)d_in[6];
    const float* P  = (const float*)d_in[7];
    float* Y = (float*)d_out;

    unsigned short* Xb  = (unsigned short*)d_ws;
    unsigned short* hh  = (unsigned short*)((char*)d_ws + XB_BYTES);
    int*            cnt = (int*)((char*)d_ws + XB_BYTES + HH_BYTES);

    // zero sync flags + xcd table (ws is poisoned before every timed call)
    hipMemsetAsync(cnt, 0, CNT_BYTES, stream);

    // K1: X -> swizzled bf16
    k_convX<<<8192, 256, 0, stream>>>(X, Xb);
    // K2: initial_h -> hh slot 0
    k_initH<<<32, 256, 0, stream>>>(h0, hh);
    // Phase 2: persistent recurrence (256 WGs)
    k_lstm<<<256, 256, 0, stream>>>(W, R, Bb, sl, h0, c0, P, Xb, hh, cnt, Y);
}